// Round 4
// baseline (37.818 us; speedup 1.0000x reference)
//
#include <hip/hip_runtime.h>

// YOLO v1 loss on MI355X — round 4.
// Wave-private LDS staging via global_load_lds (perfectly coalesced global
// traffic), no block barriers, 2-tile prefetch pipeline, wave partials to
// workspace + tiny reduce kernel.
// bounding_boxes (8192,7,7,30) f32, ground_truth (8192,7,7,30) f32.
// Output: 6 float32 scalars.

#define CH 30
#define NCELLS (8192 * 49)        // 401408
#define TCELLS 64                 // cells per wave-tile
#define TBYTES (TCELLS * CH * 4)  // 7680 bytes per array per tile
#define NTILES (NCELLS / TCELLS)  // 6272
#define BLK 256
#define WPB (BLK / 64)            // 4 waves per block
#define GRID_BLOCKS 784
#define NW (GRID_BLOCKS * WPB)    // 3136 waves; 2 tiles per wave exactly

__device__ __forceinline__ float iou_one(const float* __restrict__ B,
                                         const float* __restrict__ G,
                                         float fx, float fy) {
    float px = truncf((B[0] + fx) * 64.0f);
    float py = truncf((B[1] + fy) * 64.0f);
    float pw = truncf(B[2] * 448.0f);
    float ph = truncf(B[3] * 448.0f);
    float x1 = fmaxf(0.0f, px - pw * 0.5f);
    float y1 = fmaxf(0.0f, py - ph * 0.5f);
    float x2 = fminf(447.0f, px + pw * 0.5f);
    float y2 = fminf(447.0f, py + ph * 0.5f);
    float parea = (x2 - x1) * (y2 - y1);
    float lx = fmaxf(x1, G[5]);
    float rx = fminf(x2, G[7]);
    float uy = fmaxf(y1, G[6]);
    float dy = fminf(y2, G[8]);
    float inter = (rx - lx) * (dy - uy);
    bool valid = (rx >= lx) && (dy >= uy);
    return valid ? inter / (parea + G[9] - inter) : 0.0f;
}

// Stage one 64-cell tile (bb then gt, 15360 B contiguous in LDS) with 15
// global_load_lds_dwordx4. LDS dest is wave-uniform base + lane*16 (linear);
// per-lane global source handles the bb/gt split.
__device__ __forceinline__ void stage_tile(const char* __restrict__ bb,
                                           const char* __restrict__ gt,
                                           char* lbase, int tile, int lane) {
    const char* bbt = bb + (size_t)tile * TBYTES;
    const char* gtt = gt + (size_t)tile * TBYTES;
#pragma unroll
    for (int i = 0; i < 15; ++i) {
        int f = i * 1024 + lane * 16;
        const char* src = (f < TBYTES) ? (bbt + f) : (gtt + (f - TBYTES));
        __builtin_amdgcn_global_load_lds(
            (const __attribute__((address_space(1))) void*)src,
            (__attribute__((address_space(3))) void*)(lbase + i * 1024), 16, 0,
            0);
    }
}

__global__ __launch_bounds__(256) void yolo_v1_loss_main(
    const float* __restrict__ bbf, const float* __restrict__ gtf,
    float* __restrict__ ws) {
    __shared__ char lds[WPB][2 * TBYTES];  // 61440 B total

    const int tid = threadIdx.x;
    const int lane = tid & 63;
    const int w = tid >> 6;
    const int gw = blockIdx.x * WPB + w;  // global wave id, 0..NW-1

    const char* bb = (const char*)bbf;
    const char* gt = (const char*)gtf;
    char* lbase = lds[w];

    float a_loss = 0.f, a_coord = 0.f, a_conf = 0.f, a_cls = 0.f,
          a_iou = 0.f, a_obj = 0.f;

    stage_tile(bb, gt, lbase, gw, lane);

#pragma unroll
    for (int it = 0; it < 2; ++it) {
        const int tile = gw + it * NW;

        // tile data must be in LDS (gll is not tracked by the compiler's
        // LDS dep analysis — explicit drain)
        asm volatile("s_waitcnt vmcnt(0)" ::: "memory");
        __builtin_amdgcn_sched_barrier(0);

        // ---- LDS -> registers: 15+15 ds_read_b64 per lane ----
        float vb[CH], vg[CH];
        const float2* pb2 = (const float2*)(lbase + lane * (CH * 4));
        const float2* pg2 = (const float2*)(lbase + TBYTES + lane * (CH * 4));
#pragma unroll
        for (int i = 0; i < 15; ++i) {
            *(float2*)(vb + 2 * i) = pb2[i];
            *(float2*)(vg + 2 * i) = pg2[i];
        }

        if (it == 0) {
            // WAR: next stage overwrites this buffer — ds_reads must land first
            asm volatile("s_waitcnt lgkmcnt(0)" ::: "memory");
            __builtin_amdgcn_sched_barrier(0);
            stage_tile(bb, gt, lbase, gw + NW, lane);
        }

        // ---- per-cell math ----
        int cell = tile * TCELLS + lane;
        int b = cell / 49;
        int rem = cell - b * 49;
        int gy = rem / 7;
        int gx = rem - gy * 7;
        float fx = (float)gx, fy = (float)gy;

        const float* B = vb;
        const float* G = vg;

        float iou1 = iou_one(B, G, fx, fy);
        float iou2 = iou_one(B + 5, G, fx, fy);
        bool r1 = iou1 > iou2;
        const float* P = r1 ? B : (B + 5);
        const float* Nb = r1 ? (B + 5) : B;
        float iou = r1 ? iou1 : iou2;

        float fm = (rintf(G[4]) != 0.0f) ? 1.0f : 0.0f;
        float noobj = 0.5f * (B[4] * B[4] + B[9] * B[9]);

        float dx = P[0] - G[0];
        float dyv = P[1] - G[1];
        float dw = sqrtf(P[2]) - sqrtf(G[2]);
        float dh = sqrtf(P[3]) - sqrtf(G[3]);
        float coord = 5.0f * (dx * dx + dyv * dyv + dw * dw + dh * dh);

        float dc = P[4] - iou;
        float conf = dc * dc + 0.5f * Nb[4] * Nb[4];

        float cls = 0.f;
#pragma unroll
        for (int k = 0; k < 20; ++k) {
            float d = G[10 + k] - B[10 + k];
            cls += d * d;
        }

        float ifm = 1.0f - fm;
        a_loss += fm * (coord + conf + cls) + ifm * noobj;
        a_coord += fm * coord;
        a_conf += fm * conf + ifm * noobj;
        a_cls += fm * cls;
        a_iou += fm * iou;
        a_obj += fm;
    }

    // ---- wave reduce (64-wide), partials straight to workspace ----
#pragma unroll
    for (int off = 32; off > 0; off >>= 1) {
        a_loss += __shfl_down(a_loss, off);
        a_coord += __shfl_down(a_coord, off);
        a_conf += __shfl_down(a_conf, off);
        a_cls += __shfl_down(a_cls, off);
        a_iou += __shfl_down(a_iou, off);
        a_obj += __shfl_down(a_obj, off);
    }
    if (lane == 0) {
        ws[0 * NW + gw] = a_loss;
        ws[1 * NW + gw] = a_coord;
        ws[2 * NW + gw] = a_conf;
        ws[3 * NW + gw] = a_cls;
        ws[4 * NW + gw] = a_iou;
        ws[5 * NW + gw] = a_obj;
    }
}

// 6 waves; wave j reduces the NW partials of output j.
__global__ __launch_bounds__(384) void yolo_v1_loss_reduce(
    const float* __restrict__ ws, float* __restrict__ out) {
    const int tid = threadIdx.x;
    const int j = tid >> 6;
    const int lane = tid & 63;
    float s = 0.f;
    for (int i = lane; i < NW; i += 64) s += ws[j * NW + i];
#pragma unroll
    for (int off = 32; off > 0; off >>= 1) s += __shfl_down(s, off);
    if (lane == 0) out[j] = s;
}

extern "C" void kernel_launch(void* const* d_in, const int* in_sizes, int n_in,
                              void* d_out, int out_size, void* d_ws,
                              size_t ws_size, hipStream_t stream) {
    const float* bb = (const float*)d_in[0];
    const float* gt = (const float*)d_in[1];
    float* out = (float*)d_out;
    float* ws = (float*)d_ws;
    yolo_v1_loss_main<<<GRID_BLOCKS, BLK, 0, stream>>>(bb, gt, ws);
    yolo_v1_loss_reduce<<<1, 384, 0, stream>>>(ws, out);
}